// Round 8
// baseline (502.053 us; speedup 1.0000x reference)
//
#include <hip/hip_runtime.h>

// Problem constants: B=4, S=2048, D=1024, H=16, DK=64
#define BDIM 4
#define SDIM 2048
#define DDIM 1024
#define HDIM 16
#define DKDIM 64
#define MDIM (BDIM*SDIM)   // 8192

typedef __attribute__((ext_vector_type(8))) short bf16x8_t;
typedef __attribute__((ext_vector_type(4))) float f32x4_t;
typedef __attribute__((ext_vector_type(16))) float f32x16_t;

__device__ __forceinline__ unsigned short f2bf(float f) {
    union { float f; unsigned u; } v; v.f = f;
    unsigned r = v.u + 0x7FFFu + ((v.u >> 16) & 1u);  // RNE
    return (unsigned short)(r >> 16);
}

// Single-instruction packed f32->bf16 (m240: no builtin on gfx950, use asm)
__device__ __forceinline__ unsigned pkbf(float a, float b) {
    unsigned r;
    asm("v_cvt_pk_bf16_f32 %0, %1, %2" : "=v"(r) : "v"(a), "v"(b));
    return r;
}

// permlane32_swap, raw asm:
// after: a = {a.lanes0-31, b.lanes0-31}, b = {a.lanes32-63, b.lanes32-63}
__device__ __forceinline__ void plswap(unsigned &a, unsigned &b) {
    asm("v_permlane32_swap_b32 %0, %1" : "+v"(a), "+v"(b));
}

#if defined(__has_builtin) && __has_builtin(__builtin_amdgcn_exp2f)
#define EXP2F(x) __builtin_amdgcn_exp2f(x)
#else
#define EXP2F(x) __expf((x) * 0.69314718f)
#endif

// single-op sign-extended 1-bit extract (v_bfe_i32)
#if defined(__has_builtin) && __has_builtin(__builtin_amdgcn_sbfe)
#define SBFE1(x, p) __builtin_amdgcn_sbfe((int)(x), (p), 1)
#else
#define SBFE1(x, p) (((int)((x) << (31 - (p)))) >> 31)
#endif

#define QSCALE 0.18033688011112042f  // log2(e)/8, folded into Q projection

__device__ __forceinline__ void gl_lds16(const void* g, void* l) {
    __builtin_amdgcn_global_load_lds(
        (const __attribute__((address_space(1))) unsigned int*)g,
        (__attribute__((address_space(3))) unsigned int*)l, 16, 0, 0);
}

// ---------------- fp32 -> bf16 cast, all 7 arrays, one launch ----------------
// Sizes are powers of two: N4M = 1<<21, N4D = 1<<18 -> routing is shifts/masks.
__global__ void cvt_all(const float* __restrict__ q, const float* __restrict__ k, const float* __restrict__ v,
                        const float* __restrict__ wq, const float* __restrict__ wk,
                        const float* __restrict__ wv, const float* __restrict__ wo,
                        unsigned short* __restrict__ oq, unsigned short* __restrict__ ok, unsigned short* __restrict__ ov,
                        unsigned short* __restrict__ owq, unsigned short* __restrict__ owk,
                        unsigned short* __restrict__ owv, unsigned short* __restrict__ owo)
{
    const int N4M = 1 << 21;             // MDIM*DDIM/4
    const int N4D = 1 << 18;             // DDIM*DDIM/4
    const int total = 3 * N4M + 4 * N4D;
    for (int i = blockIdx.x * blockDim.x + threadIdx.x; i < total; i += gridDim.x * blockDim.x) {
        const float* s; unsigned short* d; int idx;
        if (i < 3 * N4M) {
            const int a = i >> 21; idx = i & (N4M - 1);
            s = a == 0 ? q : (a == 1 ? k : v);
            d = a == 0 ? oq : (a == 1 ? ok : ov);
        } else {
            const int j = i - 3 * N4M;
            const int a = j >> 18; idx = j & (N4D - 1);
            s = a == 0 ? wq : (a == 1 ? wk : (a == 2 ? wv : wo));
            d = a == 0 ? owq : (a == 1 ? owk : (a == 2 ? owv : owo));
        }
        const float4 val = ((const float4*)s)[idx];
        uint2 o;
        o.x = pkbf(val.x, val.y);
        o.y = pkbf(val.z, val.w);
        ((uint2*)d)[idx] = o;
    }
}

// ---------------- mask -> bitmask, standalone fallback ----------------
__global__ void pack_mask(const int* __restrict__ m, unsigned long long* __restrict__ bits) {
    int g = blockIdx.x * 256 + threadIdx.x;
    unsigned long long bal = __ballot(m[g] != 0);
    if ((threadIdx.x & 63) == 0) bits[g >> 6] = bal;
}

// ---------------- merged Q/K/V projection GEMMs + fused mask packing ----------------
// BRANCH-FREE K-loop + XCD-swizzled 1-D grid: each XCD gets 192 consecutive
// (z,bm,bn) tiles -> A-panels reused 8x inside one XCD's L2.
// Blocks bid >= 1536 pack the attention mask instead (BW work hidden under the
// compute-bound GEMM; HBM is ~idle during it per round-4/5 counters).
__global__ __launch_bounds__(256) void gemm_qkv(
    const unsigned short* __restrict__ A0, const unsigned short* __restrict__ A1,
    const unsigned short* __restrict__ A2,
    const unsigned short* __restrict__ B0, const unsigned short* __restrict__ B1,
    const unsigned short* __restrict__ B2,
    const float* __restrict__ bi0, const float* __restrict__ bi1, const float* __restrict__ bi2,
    unsigned short* __restrict__ C0, unsigned short* __restrict__ C1,
    unsigned short* __restrict__ C2,
    const int* __restrict__ mask, unsigned long long* __restrict__ mbits)
{
    __shared__ unsigned short As[2][128 * 32];
    __shared__ unsigned short Bs[2][128 * 32];
    const int K = DDIM, M = MDIM, N = DDIM;
    const int bid = blockIdx.x;

    if (bid >= 1536) {
        // ---- mask packing: 256 blocks x 256 threads, grid-stride ----
        // lanes hold consecutive elements -> ballot bit l = mask[g0+l]
        const int total = BDIM * SDIM * SDIM;     // 16,777,216
        int g = (bid - 1536) * 256 + threadIdx.x;
        for (; g < total; g += 256 * 256) {
            unsigned long long bal = __ballot(mask[g] != 0);
            if ((threadIdx.x & 63) == 0) mbits[g >> 6] = bal;
        }
        return;   // no barriers on this path
    }

    const int swz = (bid & 7) * 192 + (bid >> 3);
    const int z = swz >> 9;
    const int rem = swz & 511;
    const int bm = rem >> 3, bn = rem & 7;

    const unsigned short* A = z == 0 ? A0 : (z == 1 ? A1 : A2);
    const unsigned short* Bw = z == 0 ? B0 : (z == 1 ? B1 : B2);
    const float* bias = z == 0 ? bi0 : (z == 1 ? bi1 : bi2);
    unsigned short* Cb = z == 0 ? C0 : (z == 1 ? C1 : C2);
    const float scale = z == 0 ? QSCALE : 1.0f;

    const int tid = threadIdx.x;
    const int w = tid >> 6, lane = tid & 63;
    const int wr = w >> 1, wc = w & 1;
    const int quad = lane >> 4, l16 = lane & 15;

    const int rl = lane >> 2;
    const int cl = (((lane & 3) ^ ((rl >> 1) & 3)) * 8);
    const int sw = (l16 >> 1) & 3;
    const int c0 = w * 2;
    const unsigned short* gA = A + (size_t)(bm * 128 + c0 * 16 + rl) * K + cl;
    const unsigned short* gB = Bw + (size_t)(bn * 128 + c0 * 16 + rl) * K + cl;
    const int ldsoff = c0 * 512 + lane * 8;

    f32x4_t acc[4][4] = {};

    gl_lds16(gA, &As[0][ldsoff]);
    gl_lds16(gA + (size_t)16 * K, &As[0][ldsoff + 16 * 32]);
    gl_lds16(gB, &Bs[0][ldsoff]);
    gl_lds16(gB + (size_t)16 * K, &Bs[0][ldsoff + 16 * 32]);

    int cur = 0;
    for (int k0 = 0; k0 < K; k0 += 32) {
        __syncthreads();
        if (k0 + 32 < K) {
            const unsigned short* nA = gA + k0 + 32;
            const unsigned short* nB = gB + k0 + 32;
            gl_lds16(nA, &As[cur ^ 1][ldsoff]);
            gl_lds16(nA + (size_t)16 * K, &As[cur ^ 1][ldsoff + 16 * 32]);
            gl_lds16(nB, &Bs[cur ^ 1][ldsoff]);
            gl_lds16(nB + (size_t)16 * K, &Bs[cur ^ 1][ldsoff + 16 * 32]);
        }
        bf16x8_t af[4], bfr[4];
#pragma unroll
        for (int mi = 0; mi < 4; ++mi)
            af[mi] = *(const bf16x8_t*)(&As[cur][(wr * 64 + mi * 16 + l16) * 32 + (quad ^ sw) * 8]);
#pragma unroll
        for (int ni = 0; ni < 4; ++ni)
            bfr[ni] = *(const bf16x8_t*)(&Bs[cur][(wc * 64 + ni * 16 + l16) * 32 + (quad ^ sw) * 8]);
        // swapped operands (all z): D rows (reg) = N, cols (lanes) = M
#pragma unroll
        for (int mi = 0; mi < 4; ++mi)
#pragma unroll
            for (int ni = 0; ni < 4; ++ni)
                acc[mi][ni] = __builtin_amdgcn_mfma_f32_16x16x32_bf16(bfr[ni], af[mi], acc[mi][ni], 0, 0, 0);
        cur ^= 1;
    }

    if (z == 2) {
        // V^T store: row n of Vt, element m (32B segments per 16 l16-lanes).
#pragma unroll
        for (int mi = 0; mi < 4; ++mi) {
#pragma unroll
            for (int ni = 0; ni < 4; ++ni) {
                const int n0 = bn * 128 + wc * 64 + ni * 16 + quad * 4;
                const int m = bm * 128 + wr * 64 + mi * 16 + l16;
                const float4 bv4 = *(const float4*)&bias[n0];
                Cb[(size_t)(n0 + 0) * M + m] = f2bf(acc[mi][ni][0] + bv4.x);
                Cb[(size_t)(n0 + 1) * M + m] = f2bf(acc[mi][ni][1] + bv4.y);
                Cb[(size_t)(n0 + 2) * M + m] = f2bf(acc[mi][ni][2] + bv4.z);
                Cb[(size_t)(n0 + 3) * M + m] = f2bf(acc[mi][ni][3] + bv4.w);
            }
        }
    } else {
#pragma unroll
        for (int mi = 0; mi < 4; ++mi) {
#pragma unroll
            for (int ni = 0; ni < 4; ++ni) {
                const int n0 = bn * 128 + wc * 64 + ni * 16 + quad * 4;
                const int m = bm * 128 + wr * 64 + mi * 16 + l16;
                const float4 bv4 = *(const float4*)&bias[n0];
                uint2 pk2;
                pk2.x = pkbf((acc[mi][ni][0] + bv4.x) * scale, (acc[mi][ni][1] + bv4.y) * scale);
                pk2.y = pkbf((acc[mi][ni][2] + bv4.z) * scale, (acc[mi][ni][3] + bv4.w) * scale);
                *(uint2*)(Cb + (size_t)m * N + n0) = pk2;
            }
        }
    }
}

// ---------------- output projection GEMM (f32 out, coalesced float4 stores) ----------------
__global__ __launch_bounds__(256) void gemm_out(
    const unsigned short* __restrict__ A,
    const unsigned short* __restrict__ Bw,
    const float* __restrict__ bias,
    float* __restrict__ Cf)
{
    __shared__ unsigned short As[2][128 * 32];
    __shared__ unsigned short Bs[2][128 * 32];
    const int K = DDIM, N = DDIM;
    const int bid = blockIdx.x;
    const int swz = (bid & 7) * 64 + (bid >> 3);
    const int bm = swz >> 3, bn = swz & 7;
    const int tid = threadIdx.x;
    const int w = tid >> 6, lane = tid & 63;
    const int wr = w >> 1, wc = w & 1;
    const int quad = lane >> 4, l16 = lane & 15;

    const int rl = lane >> 2;
    const int cl = (((lane & 3) ^ ((rl >> 1) & 3)) * 8);
    const int sw = (l16 >> 1) & 3;
    const int c0 = w * 2;
    const unsigned short* gA = A + (size_t)(bm * 128 + c0 * 16 + rl) * K + cl;
    const unsigned short* gB = Bw + (size_t)(bn * 128 + c0 * 16 + rl) * K + cl;
    const int ldsoff = c0 * 512 + lane * 8;

    f32x4_t acc[4][4] = {};

    gl_lds16(gA, &As[0][ldsoff]);
    gl_lds16(gA + (size_t)16 * K, &As[0][ldsoff + 16 * 32]);
    gl_lds16(gB, &Bs[0][ldsoff]);
    gl_lds16(gB + (size_t)16 * K, &Bs[0][ldsoff + 16 * 32]);

    int cur = 0;
    for (int k0 = 0; k0 < K; k0 += 32) {
        __syncthreads();
        if (k0 + 32 < K) {
            const unsigned short* nA = gA + k0 + 32;
            const unsigned short* nB = gB + k0 + 32;
            gl_lds16(nA, &As[cur ^ 1][ldsoff]);
            gl_lds16(nA + (size_t)16 * K, &As[cur ^ 1][ldsoff + 16 * 32]);
            gl_lds16(nB, &Bs[cur ^ 1][ldsoff]);
            gl_lds16(nB + (size_t)16 * K, &Bs[cur ^ 1][ldsoff + 16 * 32]);
        }
        bf16x8_t af[4], bfr[4];
#pragma unroll
        for (int mi = 0; mi < 4; ++mi)
            af[mi] = *(const bf16x8_t*)(&As[cur][(wr * 64 + mi * 16 + l16) * 32 + (quad ^ sw) * 8]);
#pragma unroll
        for (int ni = 0; ni < 4; ++ni)
            bfr[ni] = *(const bf16x8_t*)(&Bs[cur][(wc * 64 + ni * 16 + l16) * 32 + (quad ^ sw) * 8]);
#pragma unroll
        for (int mi = 0; mi < 4; ++mi)
#pragma unroll
            for (int ni = 0; ni < 4; ++ni)
                acc[mi][ni] = __builtin_amdgcn_mfma_f32_16x16x32_bf16(bfr[ni], af[mi], acc[mi][ni], 0, 0, 0);
        cur ^= 1;
    }

#pragma unroll
    for (int mi = 0; mi < 4; ++mi) {
#pragma unroll
        for (int ni = 0; ni < 4; ++ni) {
            const int n0 = bn * 128 + wc * 64 + ni * 16 + quad * 4;
            const int m = bm * 128 + wr * 64 + mi * 16 + l16;
            const float4 bv4 = *(const float4*)&bias[n0];
            float4 o;
            o.x = acc[mi][ni][0] + bv4.x;
            o.y = acc[mi][ni][1] + bv4.y;
            o.z = acc[mi][ni][2] + bv4.z;
            o.w = acc[mi][ni][3] + bv4.w;
            *(float4*)(Cf + (size_t)m * N + n0) = o;
        }
    }
}

// ---------------- fused flash attention (staged, double-buffered) ----------------
// 32x32 swapped-QK^T structure.  XCD-swizzled block decode so the 16 q-tiles
// sharing one (b,h) K/V panel colocate per XCD.  The gl_lds double-buffer IS the
// pipelining mechanism (round-6 direct-load ablation: 103 -> 298 us without it).
__global__ __launch_bounds__(256, 4) void attn_kernel(
    const unsigned short* __restrict__ Qp,   // [M][D] bf16, pre-scaled by log2e/8
    const unsigned short* __restrict__ Kp,   // [M][D] bf16
    const unsigned short* __restrict__ Vt,   // [D][M] bf16 (V^T)
    const unsigned long long* __restrict__ mbits, // [B*S][32] packed mask bits
    unsigned short* __restrict__ Xa)         // [M][D] bf16
{
    __shared__ unsigned short SMEM[16384];   // 32 KB: Ks[2][4096] then Vs[2][4096]
    const int tid = threadIdx.x, w = tid >> 6, lane = tid & 63;
    const int l32 = lane & 31, hi = lane >> 5;
    // XCD-aware decode: qt fastest within an XCD's chunk
    const int bid = blockIdx.x;              // 1024
    const int swz = (bid & 7) * 128 + (bid >> 3);
    const int qt = swz & 15, h = (swz >> 4) & 15, b = swz >> 8;
    const int q0 = qt * 128;
    const int rl = lane >> 2;
    const int cl = (((lane & 3) ^ ((rl >> 1) & 3)) * 8);   // swizzled source column
    const int swl = (l32 >> 1) & 3;                        // reader swizzle
    const int lbase = (l32 >> 4) * 512 + (l32 & 15) * 32 + ((hi ^ swl) * 8);
    const int myq = b * SDIM + q0 + w * 32 + l32;          // this lane's query row

    // ---- Q fragments: direct global load (B-frag: k = dk chunk, hi*8+j) ----
    bf16x8_t qf[4];
    {
        const unsigned short* gq = Qp + (size_t)myq * DDIM + h * 64 + hi * 8;
#pragma unroll
        for (int c = 0; c < 4; ++c)
            qf[c] = *(const bf16x8_t*)(gq + c * 16);
    }

    const unsigned long long* mq = mbits + (size_t)myq * 32;

    const int cc0 = w * 2, cc1 = w * 2 + 1;
    const unsigned short* gK0 = Kp + (size_t)(b * SDIM + (cc0 & 3) * 16 + rl) * DDIM + h * 64 + (cc0 >> 2) * 32 + cl;
    const unsigned short* gK1 = Kp + (size_t)(b * SDIM + (cc1 & 3) * 16 + rl) * DDIM + h * 64 + (cc1 >> 2) * 32 + cl;
    const unsigned short* gV0 = Vt + (size_t)(h * 64 + (cc0 & 3) * 16 + rl) * MDIM + b * SDIM + (cc0 >> 2) * 32 + cl;
    const unsigned short* gV1 = Vt + (size_t)(h * 64 + (cc1 & 3) * 16 + rl) * MDIM + b * SDIM + (cc1 >> 2) * 32 + cl;
    unsigned short* dK0 = SMEM + cc0 * 512 + lane * 8;
    unsigned short* dK1 = SMEM + cc1 * 512 + lane * 8;
    unsigned short* dV0 = SMEM + 8192 + cc0 * 512 + lane * 8;
    unsigned short* dV1 = SMEM + 8192 + cc1 * 512 + lane * 8;

    // prologue: stage kt=0 into buffer 0
    gl_lds16(gK0, dK0);
    gl_lds16(gK1, dK1);
    gl_lds16(gV0, dV0);
    gl_lds16(gV1, dV1);
    unsigned long long nm = mq[0];

    f32x16_t o0 = {}, o1 = {}, o4 = {};
    union { unsigned u[4]; bf16x8_t v; } ones;
    ones.u[0] = ones.u[1] = ones.u[2] = ones.u[3] = 0x3F803F80u;

    int cur = 0;
    for (int kt = 0; kt < SDIM / 64; ++kt) {
        __syncthreads();   // buf[cur] staged + prior reads of buf[cur] done
        const unsigned long long mysh = nm >> (4 * hi);
        const unsigned mw0 = (unsigned)mysh;
        const unsigned mw1 = (unsigned)(mysh >> 32);

        if (kt + 1 < SDIM / 64) {
            const int nb = (cur ^ 1) * 4096;
            const size_t ko = (size_t)(kt + 1) * 64 * DDIM;
            const size_t vo = (size_t)(kt + 1) * 64;
            gl_lds16(gK0 + ko, dK0 + nb);
            gl_lds16(gK1 + ko, dK1 + nb);
            gl_lds16(gV0 + vo, dV0 + nb);
            gl_lds16(gV1 + vo, dV1 + nb);
            nm = mq[kt + 1];
        }
        const unsigned short* Ksb = SMEM + cur * 4096;
        const unsigned short* Vsb = SMEM + 8192 + cur * 4096;

#pragma unroll
        for (int t = 0; t < 2; ++t) {      // 32-key tiles within the 64-key block
            // S^T = K·Q^T : row = key, col = query (l32)
            f32x16_t s = {};
            __builtin_amdgcn_s_setprio(1);
#pragma unroll
            for (int c = 0; c < 4; ++c) {  // dk 16-chunks
                const bf16x8_t ak = *(const bf16x8_t*)(Ksb + (c >> 1) * 2048 + t * 1024 + (lbase ^ ((c & 1) * 16)));
                s = __builtin_amdgcn_mfma_f32_32x32x16_bf16(ak, qf[c], s, 0, 0, 0);
            }
            __builtin_amdgcn_s_setprio(0);
            // softmax: p = exp2(s) zeroed by mask bit (v_bfe_i32 sext + AND)
            const unsigned wm = t ? mw1 : mw0;
            float p[16];
#pragma unroll
            for (int r = 0; r < 16; ++r) {
                const int pos = (r & 3) + 8 * (r >> 2);
                const float pe = EXP2F(s[r]);
                const int mm = SBFE1(wm, pos);   // 0 or -1
                p[r] = __uint_as_float(__float_as_uint(pe) & (unsigned)mm);
            }
            // PV over the two 16-key chunks of this tile
#pragma unroll
            for (int c2 = 0; c2 < 2; ++c2) {
                unsigned d0 = pkbf(p[c2 * 8 + 0], p[c2 * 8 + 1]);
                unsigned d1 = pkbf(p[c2 * 8 + 2], p[c2 * 8 + 3]);
                unsigned d2 = pkbf(p[c2 * 8 + 4], p[c2 * 8 + 5]);
                unsigned d3 = pkbf(p[c2 * 8 + 6], p[c2 * 8 + 7]);
                plswap(d0, d2);   // -> frag words 0 / 2
                plswap(d1, d3);   // -> frag words 1 / 3
                union { unsigned u[4]; bf16x8_t v; } pf;
                pf.u[0] = d0; pf.u[1] = d1; pf.u[2] = d2; pf.u[3] = d3;
                const bf16x8_t va0 = *(const bf16x8_t*)(Vsb + t * 2048 + (lbase ^ (c2 * 16)));
                const bf16x8_t va1 = *(const bf16x8_t*)(Vsb + t * 2048 + 1024 + (lbase ^ (c2 * 16)));
                __builtin_amdgcn_s_setprio(1);
                o0 = __builtin_amdgcn_mfma_f32_32x32x16_bf16(va0, pf.v, o0, 0, 0, 0);
                o1 = __builtin_amdgcn_mfma_f32_32x32x16_bf16(va1, pf.v, o1, 0, 0, 0);
                o4 = __builtin_amdgcn_mfma_f32_32x32x16_bf16(ones.v, pf.v, o4, 0, 0, 0);
                __builtin_amdgcn_s_setprio(0);
            }
        }
        cur ^= 1;
    }

    // ---- epilogue: normalize, transpose O^T -> O via per-wave LDS, store ----
    __syncthreads();
    unsigned short* T = SMEM + w * 2304;  // per-wave [32 queries][72 dk shorts]
    const float rcp = 1.0f / o4[0];
#pragma unroll
    for (int pi = 0; pi < 8; ++pi) {
        const int dk = (pi & 1) * 2 + 8 * (pi >> 1) + 4 * hi;
        *(unsigned*)&T[l32 * 72 + dk]      = pkbf(o0[2 * pi] * rcp, o0[2 * pi + 1] * rcp);
        *(unsigned*)&T[l32 * 72 + 32 + dk] = pkbf(o1[2 * pi] * rcp, o1[2 * pi + 1] * rcp);
    }
    // per-wave region: LDS write->read ordered by lgkmcnt, no barrier needed
    const int rrow = lane >> 1;
    const unsigned short* Trow = SMEM + w * 2304 + rrow * 72 + (lane & 1) * 32;
    unsigned short* dst = Xa + (size_t)(b * SDIM + q0 + w * 32 + rrow) * DDIM + h * 64 + (lane & 1) * 32;
#pragma unroll
    for (int i = 0; i < 4; ++i)
        *(bf16x8_t*)(dst + i * 8) = *(const bf16x8_t*)(Trow + i * 8);
}

extern "C" void kernel_launch(void* const* d_in, const int* in_sizes, int n_in,
                              void* d_out, int out_size, void* d_ws, size_t ws_size,
                              hipStream_t stream)
{
    const float* query = (const float*)d_in[0];
    const float* key   = (const float*)d_in[1];
    const float* value = (const float*)d_in[2];
    const int*   mask  = (const int*)d_in[3];
    const float* Wq = (const float*)d_in[4];  const float* bq = (const float*)d_in[5];
    const float* Wk = (const float*)d_in[6];  const float* bk = (const float*)d_in[7];
    const float* Wv = (const float*)d_in[8];  const float* bv = (const float*)d_in[9];
    const float* Wo = (const float*)d_in[10]; const float* bo = (const float*)d_in[11];

    const size_t MD = (size_t)MDIM * DDIM;
    const size_t DD = (size_t)DDIM * DDIM;

    unsigned short* qb  = (unsigned short*)d_ws;
    unsigned short* kb  = qb + MD;
    unsigned short* vb  = kb + MD;
    unsigned short* wqb = vb + MD;
    unsigned short* wkb = wqb + DD;
    unsigned short* wvb = wkb + DD;
    unsigned short* wob = wvb + DD;
    unsigned short* Qp  = wob + DD;
    unsigned short* Kp  = Qp + MD;
    unsigned short* Vt  = Kp + MD;
    unsigned short* Xa  = Vt + MD;

    // mbits: fresh region after Xa if workspace allows (enables fusing mask
    // packing into gemm_qkv — no alias with A-reads); else fall back to the
    // qb-alias + separate launch (qb is dead after gemm_qkv in that path).
    const size_t mbits_bytes = (size_t)BDIM * SDIM * SDIM / 8;   // 2 MB
    const size_t base_bytes = (7 * MD + 4 * DD) * sizeof(unsigned short);
    const bool fuse_mask = ws_size >= base_bytes + mbits_bytes;
    unsigned long long* mbits = fuse_mask ? (unsigned long long*)(Xa + MD)
                                          : (unsigned long long*)qb;

    cvt_all<<<2048, 256, 0, stream>>>(query, key, value, Wq, Wk, Wv, Wo,
                                      qb, kb, vb, wqb, wkb, wvb, wob);

    if (fuse_mask) {
        gemm_qkv<<<1792, 256, 0, stream>>>(qb, kb, vb, wqb, wkb, wvb,
                                           bq, bk, bv, Qp, Kp, Vt, mask, mbits);
    } else {
        gemm_qkv<<<1536, 256, 0, stream>>>(qb, kb, vb, wqb, wkb, wvb,
                                           bq, bk, bv, Qp, Kp, Vt, mask, mbits);
        pack_mask<<<(BDIM * SDIM * SDIM) / 256, 256, 0, stream>>>(mask, mbits);
    }

    attn_kernel<<<BDIM * HDIM * (SDIM / 128), 256, 0, stream>>>(Qp, Kp, Vt, mbits, Xa);

    gemm_out<<<512, 256, 0, stream>>>(Xa, wob, bo, (float*)d_out);
}

// Round 9
// 412.307 us; speedup vs baseline: 1.2177x; 1.2177x over previous
//
#include <hip/hip_runtime.h>

// Problem constants: B=4, S=2048, D=1024, H=16, DK=64
#define BDIM 4
#define SDIM 2048
#define DDIM 1024
#define HDIM 16
#define DKDIM 64
#define MDIM (BDIM*SDIM)   // 8192

typedef __attribute__((ext_vector_type(8))) short bf16x8_t;
typedef __attribute__((ext_vector_type(4))) float f32x4_t;
typedef __attribute__((ext_vector_type(16))) float f32x16_t;

__device__ __forceinline__ unsigned short f2bf(float f) {
    union { float f; unsigned u; } v; v.f = f;
    unsigned r = v.u + 0x7FFFu + ((v.u >> 16) & 1u);  // RNE
    return (unsigned short)(r >> 16);
}

// Single-instruction packed f32->bf16 (m240: no builtin on gfx950, use asm)
__device__ __forceinline__ unsigned pkbf(float a, float b) {
    unsigned r;
    asm("v_cvt_pk_bf16_f32 %0, %1, %2" : "=v"(r) : "v"(a), "v"(b));
    return r;
}

// permlane32_swap, raw asm:
// after: a = {a.lanes0-31, b.lanes0-31}, b = {a.lanes32-63, b.lanes32-63}
__device__ __forceinline__ void plswap(unsigned &a, unsigned &b) {
    asm("v_permlane32_swap_b32 %0, %1" : "+v"(a), "+v"(b));
}

#if defined(__has_builtin) && __has_builtin(__builtin_amdgcn_exp2f)
#define EXP2F(x) __builtin_amdgcn_exp2f(x)
#else
#define EXP2F(x) __expf((x) * 0.69314718f)
#endif

// single-op sign-extended 1-bit extract (v_bfe_i32)
#if defined(__has_builtin) && __has_builtin(__builtin_amdgcn_sbfe)
#define SBFE1(x, p) __builtin_amdgcn_sbfe((int)(x), (p), 1)
#else
#define SBFE1(x, p) (((int)((x) << (31 - (p)))) >> 31)
#endif

#define QSCALE 0.18033688011112042f  // log2(e)/8, folded into Q projection

__device__ __forceinline__ void gl_lds16(const void* g, void* l) {
    __builtin_amdgcn_global_load_lds(
        (const __attribute__((address_space(1))) unsigned int*)g,
        (__attribute__((address_space(3))) unsigned int*)l, 16, 0, 0);
}

// ---------------- fp32 -> bf16 cast (7 arrays) + mask packing, one launch ----------------
// Both halves are pure streaming (no L2 working set) -> safe to co-schedule,
// unlike the round-8 GEMM+mask fusion which thrashed the GEMM's L2 panels.
// All region boundaries are multiples of 64 -> waves stay branch-uniform and
// ballot lane-alignment holds.  mask_total==0 disables the mask path.
__global__ void cvt_all(const float* __restrict__ q, const float* __restrict__ k, const float* __restrict__ v,
                        const float* __restrict__ wq, const float* __restrict__ wk,
                        const float* __restrict__ wv, const float* __restrict__ wo,
                        unsigned short* __restrict__ oq, unsigned short* __restrict__ ok, unsigned short* __restrict__ ov,
                        unsigned short* __restrict__ owq, unsigned short* __restrict__ owk,
                        unsigned short* __restrict__ owv, unsigned short* __restrict__ owo,
                        const int* __restrict__ mask, unsigned long long* __restrict__ mbits,
                        int mask_total)
{
    const int N4M = 1 << 21;             // MDIM*DDIM/4
    const int N4D = 1 << 18;             // DDIM*DDIM/4
    const int total_cvt = 3 * N4M + 4 * N4D;
    const int total = total_cvt + mask_total;
    const int stride = gridDim.x * blockDim.x;
    for (int i = blockIdx.x * blockDim.x + threadIdx.x; i < total; i += stride) {
        if (i < total_cvt) {
            const float* s; unsigned short* d; int idx;
            if (i < 3 * N4M) {
                const int a = i >> 21; idx = i & (N4M - 1);
                s = a == 0 ? q : (a == 1 ? k : v);
                d = a == 0 ? oq : (a == 1 ? ok : ov);
            } else {
                const int j = i - 3 * N4M;
                const int a = j >> 18; idx = j & (N4D - 1);
                s = a == 0 ? wq : (a == 1 ? wk : (a == 2 ? wv : wo));
                d = a == 0 ? owq : (a == 1 ? owk : (a == 2 ? owv : owo));
            }
            const float4 val = ((const float4*)s)[idx];
            uint2 o;
            o.x = pkbf(val.x, val.y);
            o.y = pkbf(val.z, val.w);
            ((uint2*)d)[idx] = o;
        } else {
            const int g = i - total_cvt;    // wave-consecutive, 64-aligned base
            unsigned long long bal = __ballot(mask[g] != 0);
            if ((threadIdx.x & 63) == 0) mbits[g >> 6] = bal;
        }
    }
}

// ---------------- mask -> bitmask, standalone fallback ----------------
__global__ void pack_mask(const int* __restrict__ m, unsigned long long* __restrict__ bits) {
    int g = blockIdx.x * 256 + threadIdx.x;
    unsigned long long bal = __ballot(m[g] != 0);
    if ((threadIdx.x & 63) == 0) bits[g >> 6] = bal;
}

// ---------------- merged Q/K/V projection GEMMs ----------------
// BRANCH-FREE K-loop + XCD-swizzled 1-D grid (round-5 form): each XCD gets 192
// consecutive (z,bm,bn) tiles -> A-panels reused 8x inside one XCD's L2.
__global__ __launch_bounds__(256) void gemm_qkv(
    const unsigned short* __restrict__ A0, const unsigned short* __restrict__ A1,
    const unsigned short* __restrict__ A2,
    const unsigned short* __restrict__ B0, const unsigned short* __restrict__ B1,
    const unsigned short* __restrict__ B2,
    const float* __restrict__ bi0, const float* __restrict__ bi1, const float* __restrict__ bi2,
    unsigned short* __restrict__ C0, unsigned short* __restrict__ C1,
    unsigned short* __restrict__ C2)
{
    __shared__ unsigned short As[2][128 * 32];
    __shared__ unsigned short Bs[2][128 * 32];
    const int K = DDIM, M = MDIM, N = DDIM;
    const int bid = blockIdx.x;
    const int swz = (bid & 7) * 192 + (bid >> 3);
    const int z = swz >> 9;
    const int rem = swz & 511;
    const int bm = rem >> 3, bn = rem & 7;

    const unsigned short* A = z == 0 ? A0 : (z == 1 ? A1 : A2);
    const unsigned short* Bw = z == 0 ? B0 : (z == 1 ? B1 : B2);
    const float* bias = z == 0 ? bi0 : (z == 1 ? bi1 : bi2);
    unsigned short* Cb = z == 0 ? C0 : (z == 1 ? C1 : C2);
    const float scale = z == 0 ? QSCALE : 1.0f;

    const int tid = threadIdx.x;
    const int w = tid >> 6, lane = tid & 63;
    const int wr = w >> 1, wc = w & 1;
    const int quad = lane >> 4, l16 = lane & 15;

    const int rl = lane >> 2;
    const int cl = (((lane & 3) ^ ((rl >> 1) & 3)) * 8);
    const int sw = (l16 >> 1) & 3;
    const int c0 = w * 2;
    const unsigned short* gA = A + (size_t)(bm * 128 + c0 * 16 + rl) * K + cl;
    const unsigned short* gB = Bw + (size_t)(bn * 128 + c0 * 16 + rl) * K + cl;
    const int ldsoff = c0 * 512 + lane * 8;

    f32x4_t acc[4][4] = {};

    gl_lds16(gA, &As[0][ldsoff]);
    gl_lds16(gA + (size_t)16 * K, &As[0][ldsoff + 16 * 32]);
    gl_lds16(gB, &Bs[0][ldsoff]);
    gl_lds16(gB + (size_t)16 * K, &Bs[0][ldsoff + 16 * 32]);

    int cur = 0;
    for (int k0 = 0; k0 < K; k0 += 32) {
        __syncthreads();
        if (k0 + 32 < K) {
            const unsigned short* nA = gA + k0 + 32;
            const unsigned short* nB = gB + k0 + 32;
            gl_lds16(nA, &As[cur ^ 1][ldsoff]);
            gl_lds16(nA + (size_t)16 * K, &As[cur ^ 1][ldsoff + 16 * 32]);
            gl_lds16(nB, &Bs[cur ^ 1][ldsoff]);
            gl_lds16(nB + (size_t)16 * K, &Bs[cur ^ 1][ldsoff + 16 * 32]);
        }
        bf16x8_t af[4], bfr[4];
#pragma unroll
        for (int mi = 0; mi < 4; ++mi)
            af[mi] = *(const bf16x8_t*)(&As[cur][(wr * 64 + mi * 16 + l16) * 32 + (quad ^ sw) * 8]);
#pragma unroll
        for (int ni = 0; ni < 4; ++ni)
            bfr[ni] = *(const bf16x8_t*)(&Bs[cur][(wc * 64 + ni * 16 + l16) * 32 + (quad ^ sw) * 8]);
        // swapped operands (all z): D rows (reg) = N, cols (lanes) = M
#pragma unroll
        for (int mi = 0; mi < 4; ++mi)
#pragma unroll
            for (int ni = 0; ni < 4; ++ni)
                acc[mi][ni] = __builtin_amdgcn_mfma_f32_16x16x32_bf16(bfr[ni], af[mi], acc[mi][ni], 0, 0, 0);
        cur ^= 1;
    }

    if (z == 2) {
        // V^T store: row n of Vt, element m (32B segments per 16 l16-lanes).
#pragma unroll
        for (int mi = 0; mi < 4; ++mi) {
#pragma unroll
            for (int ni = 0; ni < 4; ++ni) {
                const int n0 = bn * 128 + wc * 64 + ni * 16 + quad * 4;
                const int m = bm * 128 + wr * 64 + mi * 16 + l16;
                const float4 bv4 = *(const float4*)&bias[n0];
                Cb[(size_t)(n0 + 0) * M + m] = f2bf(acc[mi][ni][0] + bv4.x);
                Cb[(size_t)(n0 + 1) * M + m] = f2bf(acc[mi][ni][1] + bv4.y);
                Cb[(size_t)(n0 + 2) * M + m] = f2bf(acc[mi][ni][2] + bv4.z);
                Cb[(size_t)(n0 + 3) * M + m] = f2bf(acc[mi][ni][3] + bv4.w);
            }
        }
    } else {
#pragma unroll
        for (int mi = 0; mi < 4; ++mi) {
#pragma unroll
            for (int ni = 0; ni < 4; ++ni) {
                const int n0 = bn * 128 + wc * 64 + ni * 16 + quad * 4;
                const int m = bm * 128 + wr * 64 + mi * 16 + l16;
                const float4 bv4 = *(const float4*)&bias[n0];
                uint2 pk2;
                pk2.x = pkbf((acc[mi][ni][0] + bv4.x) * scale, (acc[mi][ni][1] + bv4.y) * scale);
                pk2.y = pkbf((acc[mi][ni][2] + bv4.z) * scale, (acc[mi][ni][3] + bv4.w) * scale);
                *(uint2*)(Cb + (size_t)m * N + n0) = pk2;
            }
        }
    }
}

// ---------------- output projection GEMM (f32 out, coalesced float4 stores) ----------------
__global__ __launch_bounds__(256) void gemm_out(
    const unsigned short* __restrict__ A,
    const unsigned short* __restrict__ Bw,
    const float* __restrict__ bias,
    float* __restrict__ Cf)
{
    __shared__ unsigned short As[2][128 * 32];
    __shared__ unsigned short Bs[2][128 * 32];
    const int K = DDIM, N = DDIM;
    const int bid = blockIdx.x;
    const int swz = (bid & 7) * 64 + (bid >> 3);
    const int bm = swz >> 3, bn = swz & 7;
    const int tid = threadIdx.x;
    const int w = tid >> 6, lane = tid & 63;
    const int wr = w >> 1, wc = w & 1;
    const int quad = lane >> 4, l16 = lane & 15;

    const int rl = lane >> 2;
    const int cl = (((lane & 3) ^ ((rl >> 1) & 3)) * 8);
    const int sw = (l16 >> 1) & 3;
    const int c0 = w * 2;
    const unsigned short* gA = A + (size_t)(bm * 128 + c0 * 16 + rl) * K + cl;
    const unsigned short* gB = Bw + (size_t)(bn * 128 + c0 * 16 + rl) * K + cl;
    const int ldsoff = c0 * 512 + lane * 8;

    f32x4_t acc[4][4] = {};

    gl_lds16(gA, &As[0][ldsoff]);
    gl_lds16(gA + (size_t)16 * K, &As[0][ldsoff + 16 * 32]);
    gl_lds16(gB, &Bs[0][ldsoff]);
    gl_lds16(gB + (size_t)16 * K, &Bs[0][ldsoff + 16 * 32]);

    int cur = 0;
    for (int k0 = 0; k0 < K; k0 += 32) {
        __syncthreads();
        if (k0 + 32 < K) {
            const unsigned short* nA = gA + k0 + 32;
            const unsigned short* nB = gB + k0 + 32;
            gl_lds16(nA, &As[cur ^ 1][ldsoff]);
            gl_lds16(nA + (size_t)16 * K, &As[cur ^ 1][ldsoff + 16 * 32]);
            gl_lds16(nB, &Bs[cur ^ 1][ldsoff]);
            gl_lds16(nB + (size_t)16 * K, &Bs[cur ^ 1][ldsoff + 16 * 32]);
        }
        bf16x8_t af[4], bfr[4];
#pragma unroll
        for (int mi = 0; mi < 4; ++mi)
            af[mi] = *(const bf16x8_t*)(&As[cur][(wr * 64 + mi * 16 + l16) * 32 + (quad ^ sw) * 8]);
#pragma unroll
        for (int ni = 0; ni < 4; ++ni)
            bfr[ni] = *(const bf16x8_t*)(&Bs[cur][(wc * 64 + ni * 16 + l16) * 32 + (quad ^ sw) * 8]);
#pragma unroll
        for (int mi = 0; mi < 4; ++mi)
#pragma unroll
            for (int ni = 0; ni < 4; ++ni)
                acc[mi][ni] = __builtin_amdgcn_mfma_f32_16x16x32_bf16(bfr[ni], af[mi], acc[mi][ni], 0, 0, 0);
        cur ^= 1;
    }

#pragma unroll
    for (int mi = 0; mi < 4; ++mi) {
#pragma unroll
        for (int ni = 0; ni < 4; ++ni) {
            const int n0 = bn * 128 + wc * 64 + ni * 16 + quad * 4;
            const int m = bm * 128 + wr * 64 + mi * 16 + l16;
            const float4 bv4 = *(const float4*)&bias[n0];
            float4 o;
            o.x = acc[mi][ni][0] + bv4.x;
            o.y = acc[mi][ni][1] + bv4.y;
            o.z = acc[mi][ni][2] + bv4.z;
            o.w = acc[mi][ni][3] + bv4.w;
            *(float4*)(Cf + (size_t)m * N + n0) = o;
        }
    }
}

// ---------------- fused flash attention (staged, double-buffered) ----------------
// 32x32 swapped-QK^T structure.  XCD-swizzled block decode so the 16 q-tiles
// sharing one (b,h) K/V panel colocate per XCD.  The gl_lds double-buffer IS the
// pipelining mechanism (round-6 direct-load ablation: 103 -> 298 us without it).
__global__ __launch_bounds__(256, 4) void attn_kernel(
    const unsigned short* __restrict__ Qp,   // [M][D] bf16, pre-scaled by log2e/8
    const unsigned short* __restrict__ Kp,   // [M][D] bf16
    const unsigned short* __restrict__ Vt,   // [D][M] bf16 (V^T)
    const unsigned long long* __restrict__ mbits, // [B*S][32] packed mask bits
    unsigned short* __restrict__ Xa)         // [M][D] bf16
{
    __shared__ unsigned short SMEM[16384];   // 32 KB: Ks[2][4096] then Vs[2][4096]
    const int tid = threadIdx.x, w = tid >> 6, lane = tid & 63;
    const int l32 = lane & 31, hi = lane >> 5;
    // XCD-aware decode: qt fastest within an XCD's chunk
    const int bid = blockIdx.x;              // 1024
    const int swz = (bid & 7) * 128 + (bid >> 3);
    const int qt = swz & 15, h = (swz >> 4) & 15, b = swz >> 8;
    const int q0 = qt * 128;
    const int rl = lane >> 2;
    const int cl = (((lane & 3) ^ ((rl >> 1) & 3)) * 8);   // swizzled source column
    const int swl = (l32 >> 1) & 3;                        // reader swizzle
    const int lbase = (l32 >> 4) * 512 + (l32 & 15) * 32 + ((hi ^ swl) * 8);
    const int myq = b * SDIM + q0 + w * 32 + l32;          // this lane's query row

    // ---- Q fragments: direct global load (B-frag: k = dk chunk, hi*8+j) ----
    bf16x8_t qf[4];
    {
        const unsigned short* gq = Qp + (size_t)myq * DDIM + h * 64 + hi * 8;
#pragma unroll
        for (int c = 0; c < 4; ++c)
            qf[c] = *(const bf16x8_t*)(gq + c * 16);
    }

    const unsigned long long* mq = mbits + (size_t)myq * 32;

    const int cc0 = w * 2, cc1 = w * 2 + 1;
    const unsigned short* gK0 = Kp + (size_t)(b * SDIM + (cc0 & 3) * 16 + rl) * DDIM + h * 64 + (cc0 >> 2) * 32 + cl;
    const unsigned short* gK1 = Kp + (size_t)(b * SDIM + (cc1 & 3) * 16 + rl) * DDIM + h * 64 + (cc1 >> 2) * 32 + cl;
    const unsigned short* gV0 = Vt + (size_t)(h * 64 + (cc0 & 3) * 16 + rl) * MDIM + b * SDIM + (cc0 >> 2) * 32 + cl;
    const unsigned short* gV1 = Vt + (size_t)(h * 64 + (cc1 & 3) * 16 + rl) * MDIM + b * SDIM + (cc1 >> 2) * 32 + cl;
    unsigned short* dK0 = SMEM + cc0 * 512 + lane * 8;
    unsigned short* dK1 = SMEM + cc1 * 512 + lane * 8;
    unsigned short* dV0 = SMEM + 8192 + cc0 * 512 + lane * 8;
    unsigned short* dV1 = SMEM + 8192 + cc1 * 512 + lane * 8;

    // prologue: stage kt=0 into buffer 0
    gl_lds16(gK0, dK0);
    gl_lds16(gK1, dK1);
    gl_lds16(gV0, dV0);
    gl_lds16(gV1, dV1);
    unsigned long long nm = mq[0];

    f32x16_t o0 = {}, o1 = {}, o4 = {};
    union { unsigned u[4]; bf16x8_t v; } ones;
    ones.u[0] = ones.u[1] = ones.u[2] = ones.u[3] = 0x3F803F80u;

    int cur = 0;
    for (int kt = 0; kt < SDIM / 64; ++kt) {
        __syncthreads();   // buf[cur] staged + prior reads of buf[cur] done
        const unsigned long long mysh = nm >> (4 * hi);
        const unsigned mw0 = (unsigned)mysh;
        const unsigned mw1 = (unsigned)(mysh >> 32);

        if (kt + 1 < SDIM / 64) {
            const int nb = (cur ^ 1) * 4096;
            const size_t ko = (size_t)(kt + 1) * 64 * DDIM;
            const size_t vo = (size_t)(kt + 1) * 64;
            gl_lds16(gK0 + ko, dK0 + nb);
            gl_lds16(gK1 + ko, dK1 + nb);
            gl_lds16(gV0 + vo, dV0 + nb);
            gl_lds16(gV1 + vo, dV1 + nb);
            nm = mq[kt + 1];
        }
        const unsigned short* Ksb = SMEM + cur * 4096;
        const unsigned short* Vsb = SMEM + 8192 + cur * 4096;

#pragma unroll
        for (int t = 0; t < 2; ++t) {      // 32-key tiles within the 64-key block
            // S^T = K·Q^T : row = key, col = query (l32)
            f32x16_t s = {};
            __builtin_amdgcn_s_setprio(1);
#pragma unroll
            for (int c = 0; c < 4; ++c) {  // dk 16-chunks
                const bf16x8_t ak = *(const bf16x8_t*)(Ksb + (c >> 1) * 2048 + t * 1024 + (lbase ^ ((c & 1) * 16)));
                s = __builtin_amdgcn_mfma_f32_32x32x16_bf16(ak, qf[c], s, 0, 0, 0);
            }
            __builtin_amdgcn_s_setprio(0);
            // softmax: p = exp2(s) zeroed by mask bit (v_bfe_i32 sext + AND)
            const unsigned wm = t ? mw1 : mw0;
            float p[16];
#pragma unroll
            for (int r = 0; r < 16; ++r) {
                const int pos = (r & 3) + 8 * (r >> 2);
                const float pe = EXP2F(s[r]);
                const int mm = SBFE1(wm, pos);   // 0 or -1
                p[r] = __uint_as_float(__float_as_uint(pe) & (unsigned)mm);
            }
            // PV over the two 16-key chunks of this tile
#pragma unroll
            for (int c2 = 0; c2 < 2; ++c2) {
                unsigned d0 = pkbf(p[c2 * 8 + 0], p[c2 * 8 + 1]);
                unsigned d1 = pkbf(p[c2 * 8 + 2], p[c2 * 8 + 3]);
                unsigned d2 = pkbf(p[c2 * 8 + 4], p[c2 * 8 + 5]);
                unsigned d3 = pkbf(p[c2 * 8 + 6], p[c2 * 8 + 7]);
                plswap(d0, d2);   // -> frag words 0 / 2
                plswap(d1, d3);   // -> frag words 1 / 3
                union { unsigned u[4]; bf16x8_t v; } pf;
                pf.u[0] = d0; pf.u[1] = d1; pf.u[2] = d2; pf.u[3] = d3;
                const bf16x8_t va0 = *(const bf16x8_t*)(Vsb + t * 2048 + (lbase ^ (c2 * 16)));
                const bf16x8_t va1 = *(const bf16x8_t*)(Vsb + t * 2048 + 1024 + (lbase ^ (c2 * 16)));
                __builtin_amdgcn_s_setprio(1);
                o0 = __builtin_amdgcn_mfma_f32_32x32x16_bf16(va0, pf.v, o0, 0, 0, 0);
                o1 = __builtin_amdgcn_mfma_f32_32x32x16_bf16(va1, pf.v, o1, 0, 0, 0);
                o4 = __builtin_amdgcn_mfma_f32_32x32x16_bf16(ones.v, pf.v, o4, 0, 0, 0);
                __builtin_amdgcn_s_setprio(0);
            }
        }
        cur ^= 1;
    }

    // ---- epilogue: normalize, transpose O^T -> O via per-wave LDS, store ----
    __syncthreads();
    unsigned short* T = SMEM + w * 2304;  // per-wave [32 queries][72 dk shorts]
    const float rcp = 1.0f / o4[0];
#pragma unroll
    for (int pi = 0; pi < 8; ++pi) {
        const int dk = (pi & 1) * 2 + 8 * (pi >> 1) + 4 * hi;
        *(unsigned*)&T[l32 * 72 + dk]      = pkbf(o0[2 * pi] * rcp, o0[2 * pi + 1] * rcp);
        *(unsigned*)&T[l32 * 72 + 32 + dk] = pkbf(o1[2 * pi] * rcp, o1[2 * pi + 1] * rcp);
    }
    // per-wave region: LDS write->read ordered by lgkmcnt, no barrier needed
    const int rrow = lane >> 1;
    const unsigned short* Trow = SMEM + w * 2304 + rrow * 72 + (lane & 1) * 32;
    unsigned short* dst = Xa + (size_t)(b * SDIM + q0 + w * 32 + rrow) * DDIM + h * 64 + (lane & 1) * 32;
#pragma unroll
    for (int i = 0; i < 4; ++i)
        *(bf16x8_t*)(dst + i * 8) = *(const bf16x8_t*)(Trow + i * 8);
}

extern "C" void kernel_launch(void* const* d_in, const int* in_sizes, int n_in,
                              void* d_out, int out_size, void* d_ws, size_t ws_size,
                              hipStream_t stream)
{
    const float* query = (const float*)d_in[0];
    const float* key   = (const float*)d_in[1];
    const float* value = (const float*)d_in[2];
    const int*   mask  = (const int*)d_in[3];
    const float* Wq = (const float*)d_in[4];  const float* bq = (const float*)d_in[5];
    const float* Wk = (const float*)d_in[6];  const float* bk = (const float*)d_in[7];
    const float* Wv = (const float*)d_in[8];  const float* bv = (const float*)d_in[9];
    const float* Wo = (const float*)d_in[10]; const float* bo = (const float*)d_in[11];

    const size_t MD = (size_t)MDIM * DDIM;
    const size_t DD = (size_t)DDIM * DDIM;

    unsigned short* qb  = (unsigned short*)d_ws;
    unsigned short* kb  = qb + MD;
    unsigned short* vb  = kb + MD;
    unsigned short* wqb = vb + MD;
    unsigned short* wkb = wqb + DD;
    unsigned short* wvb = wkb + DD;
    unsigned short* wob = wvb + DD;
    unsigned short* Qp  = wob + DD;
    unsigned short* Kp  = Qp + MD;
    unsigned short* Vt  = Kp + MD;
    unsigned short* Xa  = Vt + MD;

    // mbits: fresh region after Xa if workspace allows (no alias with cvt
    // outputs -> mask packing can ride inside cvt_all); else fall back to the
    // qb-alias + separate pack_mask launch after gemm_qkv (qb dead by then).
    const size_t mbits_bytes = (size_t)BDIM * SDIM * SDIM / 8;   // 2 MB
    const size_t base_bytes = (7 * MD + 4 * DD) * sizeof(unsigned short);
    const bool fuse_mask = ws_size >= base_bytes + mbits_bytes;
    unsigned long long* mbits = fuse_mask ? (unsigned long long*)(Xa + MD)
                                          : (unsigned long long*)qb;

    cvt_all<<<2048, 256, 0, stream>>>(query, key, value, Wq, Wk, Wv, Wo,
                                      qb, kb, vb, wqb, wkb, wvb, wob,
                                      mask, mbits,
                                      fuse_mask ? BDIM * SDIM * SDIM : 0);

    gemm_qkv<<<1536, 256, 0, stream>>>(qb, kb, vb, wqb, wkb, wvb,
                                       bq, bk, bv, Qp, Kp, Vt);

    if (!fuse_mask)
        pack_mask<<<(BDIM * SDIM * SDIM) / 256, 256, 0, stream>>>(mask, mbits);

    attn_kernel<<<BDIM * HDIM * (SDIM / 128), 256, 0, stream>>>(Qp, Kp, Vt, mbits, Xa);

    gemm_out<<<512, 256, 0, stream>>>(Xa, wob, bo, (float*)d_out);
}